// Round 5
// baseline (241.612 us; speedup 1.0000x reference)
//
#include <hip/hip_runtime.h>
#include <hip/hip_bf16.h>
#include <cstdint>
#include <cstddef>

// ---------------------------------------------------------------------------
// KQV2DPixel: 1x1-conv projections + flash attention, B=8, Cin=64, Cm=32,
// N=4096. fp32 in/out. Split-bf16 QK^T (hi+lo), log2-domain online softmax,
// cvt_pk+permlane32_swap P-packing, K-split x ns with reduce kernel.
// R5: revert attn loop to the R2 structure (cooperative LDS staging,
// single buffer, 2 barriers/tile -- best measured). ONE change: ns 4->8 so
// 8 blocks/CU are resident (32 waves/CU nominal) and barrier stalls of one
// block hide under the other seven. Proj: 8 threads/pixel (4 waves/SIMD).
// ---------------------------------------------------------------------------

typedef __bf16 bf16x8 __attribute__((ext_vector_type(8)));
typedef float  f32x16 __attribute__((ext_vector_type(16)));
typedef float  f32x4  __attribute__((ext_vector_type(4)));

struct alignas(16) U4 { uint32_t w[4]; };
struct alignas(8)  U2 { uint32_t w[2]; };

#define MFMA32(A, B, C) __builtin_amdgcn_mfma_f32_32x32x16_bf16((A), (B), (C), 0, 0, 0)

__device__ __forceinline__ uint16_t f2bf(float f) {
    uint32_t u = __builtin_bit_cast(uint32_t, f);
    u += 0x7fffu + ((u >> 16) & 1u);       // RNE
    return (uint16_t)(u >> 16);
}
__device__ __forceinline__ float bf2f(uint16_t h) {
    uint32_t u = ((uint32_t)h) << 16;
    return __builtin_bit_cast(float, u);
}
__device__ __forceinline__ uint32_t cvtpk(float lo, float hi) {
    uint32_t r;
    asm("v_cvt_pk_bf16_f32 %0, %1, %2" : "=v"(r) : "v"(lo), "v"(hi));
    return r;
}
__device__ __forceinline__ void swp(uint32_t& a, uint32_t& b) {
    asm("v_permlane32_swap_b32 %0, %1" : "+v"(a), "+v"(b));
}
__device__ __forceinline__ float ex2(float x) {   // 2^x
    float r;
    asm("v_exp_f32 %0, %1" : "=v"(r) : "v"(x));
    return r;
}
__device__ __forceinline__ float max3(float a, float b, float c) {
    return fmaxf(fmaxf(a, b), c);          // clang fuses to v_max3_f32
}

// ---------------------------------------------------------------------------
// Kernel 1: projections. grid 1024 x 256; 8 threads/pixel, 4 outputs each.
// Output-quarter is wave-uniform -> W rows come via scalar loads.
//   k,q: hi+lo bf16, [B][N][32]; q pre-scaled by log2(e).  v: bf16 [B][32][N].
// ---------------------------------------------------------------------------
__global__ __launch_bounds__(256) void proj_kernel(
    const float* __restrict__ x,
    const float* __restrict__ Wk, const float* __restrict__ bk,
    const float* __restrict__ Wq, const float* __restrict__ bq,
    const float* __restrict__ Wv, const float* __restrict__ bv,
    uint16_t* __restrict__ qhi, uint16_t* __restrict__ qlo,
    uint16_t* __restrict__ khi, uint16_t* __restrict__ klo,
    uint16_t* __restrict__ vt)
{
    const int g     = blockIdx.x * 256 + threadIdx.x;
    const int pixel = g & 32767;                                  // (b, n)
    const int qt    = __builtin_amdgcn_readfirstlane(g >> 15);    // 0..7, wave-uniform
    const int b     = pixel >> 12;
    const int n     = pixel & 4095;
    const int ob    = qt << 2;                                    // 4 outputs

    const float* xb = x + (size_t)b * 64 * 4096 + n;
    float xv[64];
    #pragma unroll
    for (int ci = 0; ci < 64; ++ci) xv[ci] = xb[(size_t)ci * 4096];

    #pragma unroll
    for (int pass = 0; pass < 3; ++pass) {
        const float* W    = pass == 0 ? Wk : (pass == 1 ? Wq : Wv);
        const float* bias = pass == 0 ? bk : (pass == 1 ? bq : bv);
        float acc[4];
        #pragma unroll
        for (int o = 0; o < 4; ++o) acc[o] = bias[ob + o];
        #pragma unroll
        for (int o = 0; o < 4; ++o) {
            const float* wr = W + (size_t)(ob + o) * 64;   // uniform -> s_load
            #pragma unroll
            for (int ci = 0; ci < 64; ++ci)
                acc[o] = fmaf(wr[ci], xv[ci], acc[o]);
        }
        if (pass == 2) {
            #pragma unroll
            for (int o = 0; o < 4; ++o)
                vt[((size_t)(b * 32 + ob + o)) * 4096 + n] = f2bf(acc[o]);
        } else {
            if (pass == 1) {
                #pragma unroll
                for (int o = 0; o < 4; ++o) acc[o] *= 1.44269504f;   // log2(e)
            }
            U2 hp, lp;
            #pragma unroll
            for (int j = 0; j < 2; ++j) {
                float a0 = acc[2 * j], a1 = acc[2 * j + 1];
                uint16_t h0 = f2bf(a0), h1 = f2bf(a1);
                hp.w[j] = (uint32_t)h0 | ((uint32_t)h1 << 16);
                uint16_t l0 = f2bf(a0 - bf2f(h0)), l1 = f2bf(a1 - bf2f(h1));
                lp.w[j] = (uint32_t)l0 | ((uint32_t)l1 << 16);
            }
            uint16_t* hd = (pass ? qhi : khi) + ((size_t)(b * 4096 + n)) * 32 + ob;
            uint16_t* ld = (pass ? qlo : klo) + ((size_t)(b * 4096 + n)) * 32 + ob;
            *(U2*)hd = hp;
            *(U2*)ld = lp;
        }
    }
}

// ---------------------------------------------------------------------------
// Kernel 2: flash attention with K-split (R2 structure). grid ns*256,
// 256 thr = 4 waves. b = blockIdx&7 (XCD-aligned). Per block: 128 q rows x
// (64/ns) 64-key tiles. Cooperative LDS staging, single buffer, 2 barriers.
// ---------------------------------------------------------------------------
__global__ __launch_bounds__(256, 8) void attn_kernel(
    const uint16_t* __restrict__ qhi, const uint16_t* __restrict__ qlo,
    const uint16_t* __restrict__ khi, const uint16_t* __restrict__ klo,
    const uint16_t* __restrict__ vt, float* __restrict__ out,
    float* __restrict__ opart, float* __restrict__ mpart,
    float* __restrict__ lpart, int ns)
{
    __shared__ __align__(16) uint16_t lkh[64 * 40];   // K hi tile, 80B rows
    __shared__ __align__(16) uint16_t lkl[64 * 40];   // K lo tile
    __shared__ __align__(16) uint16_t lvt[32 * 72];   // V^T tile, 144B rows

    const int blk    = blockIdx.x;
    const int b      = blk & 7;                 // XCD-aligned batch
    const int rest   = blk >> 3;
    const int qblk   = rest & 31;
    const int ksp    = rest >> 5;               // 0..ns-1
    const int ntiles = 64 / ns;
    const int kb0    = ksp * ntiles;
    const int kb1    = kb0 + ntiles;

    const int tid  = threadIdx.x;
    const int wv   = tid >> 6;
    const int lane = tid & 63;
    const int l31  = lane & 31;
    const int h32  = lane >> 5;
    const int qrow = qblk * 128 + wv * 32 + l31;

    bf16x8 qh0, qh1, ql0, ql1;
    {
        const uint16_t* r = qhi + ((size_t)(b * 4096 + qrow)) * 32;
        qh0 = __builtin_bit_cast(bf16x8, *(const U4*)(r + h32 * 8));
        qh1 = __builtin_bit_cast(bf16x8, *(const U4*)(r + 16 + h32 * 8));
        const uint16_t* r2 = qlo + ((size_t)(b * 4096 + qrow)) * 32;
        ql0 = __builtin_bit_cast(bf16x8, *(const U4*)(r2 + h32 * 8));
        ql1 = __builtin_bit_cast(bf16x8, *(const U4*)(r2 + 16 + h32 * 8));
    }

    f32x16 oacc;
    #pragma unroll
    for (int i = 0; i < 16; ++i) oacc[i] = 0.f;
    float m_run = -3.0e38f, l_run = 0.f;

    const U4* gkh = (const U4*)(khi + ((size_t)b * 4096) * 32);
    const U4* gkl = (const U4*)(klo + ((size_t)b * 4096) * 32);
    const uint16_t* gv = vt + ((size_t)b * 32) * 4096;

    #pragma unroll 1
    for (int kb = kb0; kb < kb1; ++kb) {
        // ---- stage K hi/lo (64x32) and V^T (32x64) ----
        {
            U4 a = gkh[kb * 256 + tid];
            U4 c = gkl[kb * 256 + tid];
            U4 v = *(const U4*)(gv + ((size_t)(tid >> 3)) * 4096 + kb * 64 + (tid & 7) * 8);
            *(U4*)((char*)lkh + (tid >> 2) * 80 + (tid & 3) * 16) = a;
            *(U4*)((char*)lkl + (tid >> 2) * 80 + (tid & 3) * 16) = c;
            *(U4*)((char*)lvt + (tid >> 3) * 144 + (tid & 7) * 16) = v;
        }
        __syncthreads();

        // ---- QK^T, both 32-key halves (independent MFMA chains) ----
        f32x16 s0, s1;
        #pragma unroll
        for (int i = 0; i < 16; ++i) { s0[i] = 0.f; s1[i] = 0.f; }
        {
            const char* kr = (const char*)lkh + l31 * 80 + h32 * 16;
            const char* lr = (const char*)lkl + l31 * 80 + h32 * 16;
            bf16x8 a0 = __builtin_bit_cast(bf16x8, *(const U4*)kr);
            bf16x8 a1 = __builtin_bit_cast(bf16x8, *(const U4*)(kr + 32));
            bf16x8 b0 = __builtin_bit_cast(bf16x8, *(const U4*)lr);
            bf16x8 b1 = __builtin_bit_cast(bf16x8, *(const U4*)(lr + 32));
            s0 = MFMA32(a0, qh0, s0);
            s0 = MFMA32(a1, qh1, s0);
            s0 = MFMA32(b0, qh0, s0);
            s0 = MFMA32(b1, qh1, s0);
            s0 = MFMA32(a0, ql0, s0);
            s0 = MFMA32(a1, ql1, s0);
        }
        {
            const char* kr = (const char*)lkh + (32 + l31) * 80 + h32 * 16;
            const char* lr = (const char*)lkl + (32 + l31) * 80 + h32 * 16;
            bf16x8 a0 = __builtin_bit_cast(bf16x8, *(const U4*)kr);
            bf16x8 a1 = __builtin_bit_cast(bf16x8, *(const U4*)(kr + 32));
            bf16x8 b0 = __builtin_bit_cast(bf16x8, *(const U4*)lr);
            bf16x8 b1 = __builtin_bit_cast(bf16x8, *(const U4*)(lr + 32));
            s1 = MFMA32(a0, qh0, s1);
            s1 = MFMA32(a1, qh1, s1);
            s1 = MFMA32(b0, qh0, s1);
            s1 = MFMA32(b1, qh1, s1);
            s1 = MFMA32(a0, ql0, s1);
            s1 = MFMA32(a1, ql1, s1);
        }

        // ---- one online-softmax update per 64 keys (log2 domain) ----
        float mx[4];
        #pragma unroll
        for (int i = 0; i < 4; ++i)
            mx[i] = max3(max3(s0[i], s0[i + 4], s0[i + 8]),
                         max3(s0[i + 12], s1[i], s1[i + 4]),
                         fmaxf(s1[i + 8], s1[i + 12]));
        float pm = fmaxf(max3(mx[0], mx[1], mx[2]), mx[3]);
        pm = fmaxf(pm, __shfl_xor(pm, 32));

        if (__any(pm > m_run)) {          // skip rescale when no row grew
            float mn  = fmaxf(m_run, pm);
            float scl = ex2(m_run - mn);
            l_run *= scl;
            #pragma unroll
            for (int i = 0; i < 16; ++i) oacc[i] *= scl;
            m_run = mn;
        }

        #pragma unroll
        for (int i = 0; i < 16; ++i) {
            s0[i] = ex2(s0[i] - m_run);
            s1[i] = ex2(s1[i] - m_run);
        }
        float sm[8];
        #pragma unroll
        for (int i = 0; i < 8; ++i)
            sm[i] = (s0[i] + s0[i + 8]) + (s1[i] + s1[i + 8]);
        #pragma unroll
        for (int i = 0; i < 4; ++i) sm[i] += sm[i + 4];
        float rs = (sm[0] + sm[2]) + (sm[1] + sm[3]);
        rs += __shfl_xor(rs, 32);
        l_run += rs;

        // ---- pack P -> 4 bf16x8 B-fragments (cvt_pk + permlane32_swap) ----
        U4 f1, f2, f3, f4;
        {
            uint32_t A = cvtpk(s0[0], s0[1]),  B = cvtpk(s0[4], s0[5]);   swp(A, B);
            uint32_t C = cvtpk(s0[2], s0[3]),  D = cvtpk(s0[6], s0[7]);   swp(C, D);
            f1.w[0] = A; f1.w[1] = C; f1.w[2] = B; f1.w[3] = D;
            A = cvtpk(s0[8], s0[9]);   B = cvtpk(s0[12], s0[13]);  swp(A, B);
            C = cvtpk(s0[10], s0[11]); D = cvtpk(s0[14], s0[15]);  swp(C, D);
            f2.w[0] = A; f2.w[1] = C; f2.w[2] = B; f2.w[3] = D;
            A = cvtpk(s1[0], s1[1]);   B = cvtpk(s1[4], s1[5]);    swp(A, B);
            C = cvtpk(s1[2], s1[3]);   D = cvtpk(s1[6], s1[7]);    swp(C, D);
            f3.w[0] = A; f3.w[1] = C; f3.w[2] = B; f3.w[3] = D;
            A = cvtpk(s1[8], s1[9]);   B = cvtpk(s1[12], s1[13]);  swp(A, B);
            C = cvtpk(s1[10], s1[11]); D = cvtpk(s1[14], s1[15]);  swp(C, D);
            f4.w[0] = A; f4.w[1] = C; f4.w[2] = B; f4.w[3] = D;
        }

        // ---- PV: O^T[c][q] += V^T * P^T  (4 MFMAs over 64 keys) ----
        {
            const char* vr = (const char*)lvt + l31 * 144 + h32 * 16;
            bf16x8 v0 = __builtin_bit_cast(bf16x8, *(const U4*)vr);
            bf16x8 v1 = __builtin_bit_cast(bf16x8, *(const U4*)(vr + 32));
            bf16x8 v2 = __builtin_bit_cast(bf16x8, *(const U4*)(vr + 64));
            bf16x8 v3 = __builtin_bit_cast(bf16x8, *(const U4*)(vr + 96));
            oacc = MFMA32(v0, __builtin_bit_cast(bf16x8, f1), oacc);
            oacc = MFMA32(v1, __builtin_bit_cast(bf16x8, f2), oacc);
            oacc = MFMA32(v2, __builtin_bit_cast(bf16x8, f3), oacc);
            oacc = MFMA32(v3, __builtin_bit_cast(bf16x8, f4), oacc);
        }
        __syncthreads();
    }

    // ---- epilogue ----
    if (ns == 1) {
        const float inv = 1.f / l_run;
        float* ob = out + ((size_t)b * 32) * 4096 + qrow;
        #pragma unroll
        for (int i = 0; i < 16; ++i) {
            int c = (i & 3) + 8 * (i >> 2) + 4 * h32;
            ob[(size_t)c * 4096] = oacc[i] * inv;
        }
    } else {
        float* op = opart + ((size_t)((ksp * 8 + b) * 32)) * 4096 + qrow;
        #pragma unroll
        for (int i = 0; i < 16; ++i) {
            int c = (i & 3) + 8 * (i >> 2) + 4 * h32;
            op[(size_t)c * 4096] = oacc[i];
        }
        if (h32 == 0) {
            mpart[((size_t)(ksp * 8 + b)) * 4096 + qrow] = m_run;
            lpart[((size_t)(ksp * 8 + b)) * 4096 + qrow] = l_run;
        }
    }
}

// ---------------------------------------------------------------------------
// Kernel 3: combine K-split partials. thread = (b, c, 4 pixels).
// ---------------------------------------------------------------------------
__global__ __launch_bounds__(256) void reduce_kernel(
    const float* __restrict__ opart, const float* __restrict__ mpart,
    const float* __restrict__ lpart, float* __restrict__ out, int ns)
{
    const int idx = blockIdx.x * 256 + threadIdx.x;   // 262144 quads
    const int nq  = idx & 1023;
    const int c   = (idx >> 10) & 31;
    const int b   = idx >> 15;
    const size_t noff = (size_t)nq * 4;

    f32x4 M;
    #pragma unroll
    for (int e = 0; e < 4; ++e) M[e] = -3.0e38f;
    for (int s = 0; s < ns; ++s) {
        f32x4 mm = *(const f32x4*)(mpart + ((size_t)(s * 8 + b)) * 4096 + noff);
        #pragma unroll
        for (int e = 0; e < 4; ++e) M[e] = fmaxf(M[e], mm[e]);
    }
    f32x4 L, O;
    #pragma unroll
    for (int e = 0; e < 4; ++e) { L[e] = 0.f; O[e] = 0.f; }
    for (int s = 0; s < ns; ++s) {
        f32x4 mm = *(const f32x4*)(mpart + ((size_t)(s * 8 + b)) * 4096 + noff);
        f32x4 ll = *(const f32x4*)(lpart + ((size_t)(s * 8 + b)) * 4096 + noff);
        f32x4 oo = *(const f32x4*)(opart + ((size_t)((s * 8 + b) * 32 + c)) * 4096 + noff);
        #pragma unroll
        for (int e = 0; e < 4; ++e) {
            float w = ex2(mm[e] - M[e]);
            L[e] += ll[e] * w;
            O[e] += oo[e] * w;
        }
    }
    f32x4 r;
    #pragma unroll
    for (int e = 0; e < 4; ++e) r[e] = O[e] / L[e];
    *(f32x4*)(out + ((size_t)(b * 32 + c)) * 4096 + noff) = r;
}

// ---------------------------------------------------------------------------
extern "C" void kernel_launch(void* const* d_in, const int* in_sizes, int n_in,
                              void* d_out, int out_size, void* d_ws, size_t ws_size,
                              hipStream_t stream)
{
    (void)in_sizes; (void)n_in; (void)out_size;
    const float* x  = (const float*)d_in[0];
    const float* Wk = (const float*)d_in[1];
    const float* bk = (const float*)d_in[2];
    const float* Wq = (const float*)d_in[3];
    const float* bq = (const float*)d_in[4];
    const float* Wv = (const float*)d_in[5];
    const float* bv = (const float*)d_in[6];
    float* out = (float*)d_out;

    char* ws = (char*)d_ws;
    const size_t SZ = (size_t)8 * 4096 * 32 * 2;   // 2 MB per bf16 buffer
    uint16_t* qhi = (uint16_t*)(ws);
    uint16_t* qlo = (uint16_t*)(ws + SZ);
    uint16_t* khi = (uint16_t*)(ws + 2 * SZ);
    uint16_t* klo = (uint16_t*)(ws + 3 * SZ);
    uint16_t* vt  = (uint16_t*)(ws + 4 * SZ);
    const size_t base = 5 * SZ;                    // 10 MB

    const size_t OB  = (size_t)8 * 32 * 4096 * 4;  // 4 MB per split (O^T)
    const size_t MB_ = (size_t)8 * 4096 * 4;       // 128 KB per split (m or l)
    int ns = 1;
    if      (ws_size >= base + 8 * (OB + 2 * MB_)) ns = 8;
    else if (ws_size >= base + 4 * (OB + 2 * MB_)) ns = 4;
    else if (ws_size >= base + 2 * (OB + 2 * MB_)) ns = 2;

    float* opart = (float*)(ws + base);
    float* mpart = (float*)(ws + base + (size_t)ns * OB);
    float* lpart = (float*)(ws + base + (size_t)ns * OB + (size_t)ns * MB_);

    proj_kernel<<<1024, 256, 0, stream>>>(x, Wk, bk, Wq, bq, Wv, bv,
                                          qhi, qlo, khi, klo, vt);
    attn_kernel<<<ns * 256, 256, 0, stream>>>(qhi, qlo, khi, klo, vt, out,
                                              opart, mpart, lpart, ns);
    if (ns > 1)
        reduce_kernel<<<1024, 256, 0, stream>>>(opart, mpart, lpart, out, ns);
}

// Round 6
// 87.869 us; speedup vs baseline: 2.7497x; 2.7497x over previous
//
#include <hip/hip_runtime.h>
#include <hip/hip_bf16.h>
#include <cstdint>
#include <cstddef>

// ---------------------------------------------------------------------------
// KQV2DPixel: 1x1-conv projections + flash attention, B=8, Cin=64, Cm=32,
// N=4096. fp32 in/out. Split-bf16 QK^T (hi+lo), log2-domain online softmax,
// cvt_pk+permlane32_swap P-packing, K-split x ns with reduce kernel.
// R6: R5 with the launch-bounds bug fixed. __launch_bounds__(256,8) had
// capped VGPR at 32 -> scratch spills (543 MB WRITE_SIZE, 220 us). At the
// kernel's natural VGPR=56, 8 blocks/CU (ns=8 grid) fit WITHOUT any bound:
// 8 waves/SIMD x 56 = 448 <= 512 VGPRs, 8 x 14.8 KB = 119 KB <= 160 KB LDS.
// ---------------------------------------------------------------------------

typedef __bf16 bf16x8 __attribute__((ext_vector_type(8)));
typedef float  f32x16 __attribute__((ext_vector_type(16)));
typedef float  f32x4  __attribute__((ext_vector_type(4)));

struct alignas(16) U4 { uint32_t w[4]; };
struct alignas(8)  U2 { uint32_t w[2]; };

#define MFMA32(A, B, C) __builtin_amdgcn_mfma_f32_32x32x16_bf16((A), (B), (C), 0, 0, 0)

__device__ __forceinline__ uint16_t f2bf(float f) {
    uint32_t u = __builtin_bit_cast(uint32_t, f);
    u += 0x7fffu + ((u >> 16) & 1u);       // RNE
    return (uint16_t)(u >> 16);
}
__device__ __forceinline__ float bf2f(uint16_t h) {
    uint32_t u = ((uint32_t)h) << 16;
    return __builtin_bit_cast(float, u);
}
__device__ __forceinline__ uint32_t cvtpk(float lo, float hi) {
    uint32_t r;
    asm("v_cvt_pk_bf16_f32 %0, %1, %2" : "=v"(r) : "v"(lo), "v"(hi));
    return r;
}
__device__ __forceinline__ void swp(uint32_t& a, uint32_t& b) {
    asm("v_permlane32_swap_b32 %0, %1" : "+v"(a), "+v"(b));
}
__device__ __forceinline__ float ex2(float x) {   // 2^x
    float r;
    asm("v_exp_f32 %0, %1" : "=v"(r) : "v"(x));
    return r;
}
__device__ __forceinline__ float max3(float a, float b, float c) {
    return fmaxf(fmaxf(a, b), c);          // clang fuses to v_max3_f32
}

// ---------------------------------------------------------------------------
// Kernel 1: projections. grid 1024 x 256; 8 threads/pixel, 4 outputs each.
// Output-quarter is wave-uniform -> W rows come via scalar loads.
//   k,q: hi+lo bf16, [B][N][32]; q pre-scaled by log2(e).  v: bf16 [B][32][N].
// ---------------------------------------------------------------------------
__global__ __launch_bounds__(256) void proj_kernel(
    const float* __restrict__ x,
    const float* __restrict__ Wk, const float* __restrict__ bk,
    const float* __restrict__ Wq, const float* __restrict__ bq,
    const float* __restrict__ Wv, const float* __restrict__ bv,
    uint16_t* __restrict__ qhi, uint16_t* __restrict__ qlo,
    uint16_t* __restrict__ khi, uint16_t* __restrict__ klo,
    uint16_t* __restrict__ vt)
{
    const int g     = blockIdx.x * 256 + threadIdx.x;
    const int pixel = g & 32767;                                  // (b, n)
    const int qt    = __builtin_amdgcn_readfirstlane(g >> 15);    // 0..7, wave-uniform
    const int b     = pixel >> 12;
    const int n     = pixel & 4095;
    const int ob    = qt << 2;                                    // 4 outputs

    const float* xb = x + (size_t)b * 64 * 4096 + n;
    float xv[64];
    #pragma unroll
    for (int ci = 0; ci < 64; ++ci) xv[ci] = xb[(size_t)ci * 4096];

    #pragma unroll
    for (int pass = 0; pass < 3; ++pass) {
        const float* W    = pass == 0 ? Wk : (pass == 1 ? Wq : Wv);
        const float* bias = pass == 0 ? bk : (pass == 1 ? bq : bv);
        float acc[4];
        #pragma unroll
        for (int o = 0; o < 4; ++o) acc[o] = bias[ob + o];
        #pragma unroll
        for (int o = 0; o < 4; ++o) {
            const float* wr = W + (size_t)(ob + o) * 64;   // uniform -> s_load
            #pragma unroll
            for (int ci = 0; ci < 64; ++ci)
                acc[o] = fmaf(wr[ci], xv[ci], acc[o]);
        }
        if (pass == 2) {
            #pragma unroll
            for (int o = 0; o < 4; ++o)
                vt[((size_t)(b * 32 + ob + o)) * 4096 + n] = f2bf(acc[o]);
        } else {
            if (pass == 1) {
                #pragma unroll
                for (int o = 0; o < 4; ++o) acc[o] *= 1.44269504f;   // log2(e)
            }
            U2 hp, lp;
            #pragma unroll
            for (int j = 0; j < 2; ++j) {
                float a0 = acc[2 * j], a1 = acc[2 * j + 1];
                uint16_t h0 = f2bf(a0), h1 = f2bf(a1);
                hp.w[j] = (uint32_t)h0 | ((uint32_t)h1 << 16);
                uint16_t l0 = f2bf(a0 - bf2f(h0)), l1 = f2bf(a1 - bf2f(h1));
                lp.w[j] = (uint32_t)l0 | ((uint32_t)l1 << 16);
            }
            uint16_t* hd = (pass ? qhi : khi) + ((size_t)(b * 4096 + n)) * 32 + ob;
            uint16_t* ld = (pass ? qlo : klo) + ((size_t)(b * 4096 + n)) * 32 + ob;
            *(U2*)hd = hp;
            *(U2*)ld = lp;
        }
    }
}

// ---------------------------------------------------------------------------
// Kernel 2: flash attention with K-split (R2 structure). grid ns*256,
// 256 thr = 4 waves. b = blockIdx&7 (XCD-aligned). Per block: 128 q rows x
// (64/ns) 64-key tiles. Cooperative LDS staging, single buffer, 2 barriers.
// NOTE: launch bound is (256,4) -> VGPR cap 128; kernel uses ~56, so the
// HARDWARE fits 8 blocks/CU when the grid provides them (ns=8). Do NOT
// raise the 2nd arg to 8: it caps VGPR at 64- and forces scratch spills.
// ---------------------------------------------------------------------------
__global__ __launch_bounds__(256, 4) void attn_kernel(
    const uint16_t* __restrict__ qhi, const uint16_t* __restrict__ qlo,
    const uint16_t* __restrict__ khi, const uint16_t* __restrict__ klo,
    const uint16_t* __restrict__ vt, float* __restrict__ out,
    float* __restrict__ opart, float* __restrict__ mpart,
    float* __restrict__ lpart, int ns)
{
    __shared__ __align__(16) uint16_t lkh[64 * 40];   // K hi tile, 80B rows
    __shared__ __align__(16) uint16_t lkl[64 * 40];   // K lo tile
    __shared__ __align__(16) uint16_t lvt[32 * 72];   // V^T tile, 144B rows

    const int blk    = blockIdx.x;
    const int b      = blk & 7;                 // XCD-aligned batch
    const int rest   = blk >> 3;
    const int qblk   = rest & 31;
    const int ksp    = rest >> 5;               // 0..ns-1
    const int ntiles = 64 / ns;
    const int kb0    = ksp * ntiles;
    const int kb1    = kb0 + ntiles;

    const int tid  = threadIdx.x;
    const int wv   = tid >> 6;
    const int lane = tid & 63;
    const int l31  = lane & 31;
    const int h32  = lane >> 5;
    const int qrow = qblk * 128 + wv * 32 + l31;

    bf16x8 qh0, qh1, ql0, ql1;
    {
        const uint16_t* r = qhi + ((size_t)(b * 4096 + qrow)) * 32;
        qh0 = __builtin_bit_cast(bf16x8, *(const U4*)(r + h32 * 8));
        qh1 = __builtin_bit_cast(bf16x8, *(const U4*)(r + 16 + h32 * 8));
        const uint16_t* r2 = qlo + ((size_t)(b * 4096 + qrow)) * 32;
        ql0 = __builtin_bit_cast(bf16x8, *(const U4*)(r2 + h32 * 8));
        ql1 = __builtin_bit_cast(bf16x8, *(const U4*)(r2 + 16 + h32 * 8));
    }

    f32x16 oacc;
    #pragma unroll
    for (int i = 0; i < 16; ++i) oacc[i] = 0.f;
    float m_run = -3.0e38f, l_run = 0.f;

    const U4* gkh = (const U4*)(khi + ((size_t)b * 4096) * 32);
    const U4* gkl = (const U4*)(klo + ((size_t)b * 4096) * 32);
    const uint16_t* gv = vt + ((size_t)b * 32) * 4096;

    #pragma unroll 1
    for (int kb = kb0; kb < kb1; ++kb) {
        // ---- stage K hi/lo (64x32) and V^T (32x64) ----
        {
            U4 a = gkh[kb * 256 + tid];
            U4 c = gkl[kb * 256 + tid];
            U4 v = *(const U4*)(gv + ((size_t)(tid >> 3)) * 4096 + kb * 64 + (tid & 7) * 8);
            *(U4*)((char*)lkh + (tid >> 2) * 80 + (tid & 3) * 16) = a;
            *(U4*)((char*)lkl + (tid >> 2) * 80 + (tid & 3) * 16) = c;
            *(U4*)((char*)lvt + (tid >> 3) * 144 + (tid & 7) * 16) = v;
        }
        __syncthreads();

        // ---- QK^T, both 32-key halves (independent MFMA chains) ----
        f32x16 s0, s1;
        #pragma unroll
        for (int i = 0; i < 16; ++i) { s0[i] = 0.f; s1[i] = 0.f; }
        {
            const char* kr = (const char*)lkh + l31 * 80 + h32 * 16;
            const char* lr = (const char*)lkl + l31 * 80 + h32 * 16;
            bf16x8 a0 = __builtin_bit_cast(bf16x8, *(const U4*)kr);
            bf16x8 a1 = __builtin_bit_cast(bf16x8, *(const U4*)(kr + 32));
            bf16x8 b0 = __builtin_bit_cast(bf16x8, *(const U4*)lr);
            bf16x8 b1 = __builtin_bit_cast(bf16x8, *(const U4*)(lr + 32));
            s0 = MFMA32(a0, qh0, s0);
            s0 = MFMA32(a1, qh1, s0);
            s0 = MFMA32(b0, qh0, s0);
            s0 = MFMA32(b1, qh1, s0);
            s0 = MFMA32(a0, ql0, s0);
            s0 = MFMA32(a1, ql1, s0);
        }
        {
            const char* kr = (const char*)lkh + (32 + l31) * 80 + h32 * 16;
            const char* lr = (const char*)lkl + (32 + l31) * 80 + h32 * 16;
            bf16x8 a0 = __builtin_bit_cast(bf16x8, *(const U4*)kr);
            bf16x8 a1 = __builtin_bit_cast(bf16x8, *(const U4*)(kr + 32));
            bf16x8 b0 = __builtin_bit_cast(bf16x8, *(const U4*)lr);
            bf16x8 b1 = __builtin_bit_cast(bf16x8, *(const U4*)(lr + 32));
            s1 = MFMA32(a0, qh0, s1);
            s1 = MFMA32(a1, qh1, s1);
            s1 = MFMA32(b0, qh0, s1);
            s1 = MFMA32(b1, qh1, s1);
            s1 = MFMA32(a0, ql0, s1);
            s1 = MFMA32(a1, ql1, s1);
        }

        // ---- one online-softmax update per 64 keys (log2 domain) ----
        float mx[4];
        #pragma unroll
        for (int i = 0; i < 4; ++i)
            mx[i] = max3(max3(s0[i], s0[i + 4], s0[i + 8]),
                         max3(s0[i + 12], s1[i], s1[i + 4]),
                         fmaxf(s1[i + 8], s1[i + 12]));
        float pm = fmaxf(max3(mx[0], mx[1], mx[2]), mx[3]);
        pm = fmaxf(pm, __shfl_xor(pm, 32));

        if (__any(pm > m_run)) {          // skip rescale when no row grew
            float mn  = fmaxf(m_run, pm);
            float scl = ex2(m_run - mn);
            l_run *= scl;
            #pragma unroll
            for (int i = 0; i < 16; ++i) oacc[i] *= scl;
            m_run = mn;
        }

        #pragma unroll
        for (int i = 0; i < 16; ++i) {
            s0[i] = ex2(s0[i] - m_run);
            s1[i] = ex2(s1[i] - m_run);
        }
        float sm[8];
        #pragma unroll
        for (int i = 0; i < 8; ++i)
            sm[i] = (s0[i] + s0[i + 8]) + (s1[i] + s1[i + 8]);
        #pragma unroll
        for (int i = 0; i < 4; ++i) sm[i] += sm[i + 4];
        float rs = (sm[0] + sm[2]) + (sm[1] + sm[3]);
        rs += __shfl_xor(rs, 32);
        l_run += rs;

        // ---- pack P -> 4 bf16x8 B-fragments (cvt_pk + permlane32_swap) ----
        U4 f1, f2, f3, f4;
        {
            uint32_t A = cvtpk(s0[0], s0[1]),  B = cvtpk(s0[4], s0[5]);   swp(A, B);
            uint32_t C = cvtpk(s0[2], s0[3]),  D = cvtpk(s0[6], s0[7]);   swp(C, D);
            f1.w[0] = A; f1.w[1] = C; f1.w[2] = B; f1.w[3] = D;
            A = cvtpk(s0[8], s0[9]);   B = cvtpk(s0[12], s0[13]);  swp(A, B);
            C = cvtpk(s0[10], s0[11]); D = cvtpk(s0[14], s0[15]);  swp(C, D);
            f2.w[0] = A; f2.w[1] = C; f2.w[2] = B; f2.w[3] = D;
            A = cvtpk(s1[0], s1[1]);   B = cvtpk(s1[4], s1[5]);    swp(A, B);
            C = cvtpk(s1[2], s1[3]);   D = cvtpk(s1[6], s1[7]);    swp(C, D);
            f3.w[0] = A; f3.w[1] = C; f3.w[2] = B; f3.w[3] = D;
            A = cvtpk(s1[8], s1[9]);   B = cvtpk(s1[12], s1[13]);  swp(A, B);
            C = cvtpk(s1[10], s1[11]); D = cvtpk(s1[14], s1[15]);  swp(C, D);
            f4.w[0] = A; f4.w[1] = C; f4.w[2] = B; f4.w[3] = D;
        }

        // ---- PV: O^T[c][q] += V^T * P^T  (4 MFMAs over 64 keys) ----
        {
            const char* vr = (const char*)lvt + l31 * 144 + h32 * 16;
            bf16x8 v0 = __builtin_bit_cast(bf16x8, *(const U4*)vr);
            bf16x8 v1 = __builtin_bit_cast(bf16x8, *(const U4*)(vr + 32));
            bf16x8 v2 = __builtin_bit_cast(bf16x8, *(const U4*)(vr + 64));
            bf16x8 v3 = __builtin_bit_cast(bf16x8, *(const U4*)(vr + 96));
            oacc = MFMA32(v0, __builtin_bit_cast(bf16x8, f1), oacc);
            oacc = MFMA32(v1, __builtin_bit_cast(bf16x8, f2), oacc);
            oacc = MFMA32(v2, __builtin_bit_cast(bf16x8, f3), oacc);
            oacc = MFMA32(v3, __builtin_bit_cast(bf16x8, f4), oacc);
        }
        __syncthreads();
    }

    // ---- epilogue ----
    if (ns == 1) {
        const float inv = 1.f / l_run;
        float* ob = out + ((size_t)b * 32) * 4096 + qrow;
        #pragma unroll
        for (int i = 0; i < 16; ++i) {
            int c = (i & 3) + 8 * (i >> 2) + 4 * h32;
            ob[(size_t)c * 4096] = oacc[i] * inv;
        }
    } else {
        float* op = opart + ((size_t)((ksp * 8 + b) * 32)) * 4096 + qrow;
        #pragma unroll
        for (int i = 0; i < 16; ++i) {
            int c = (i & 3) + 8 * (i >> 2) + 4 * h32;
            op[(size_t)c * 4096] = oacc[i];
        }
        if (h32 == 0) {
            mpart[((size_t)(ksp * 8 + b)) * 4096 + qrow] = m_run;
            lpart[((size_t)(ksp * 8 + b)) * 4096 + qrow] = l_run;
        }
    }
}

// ---------------------------------------------------------------------------
// Kernel 3: combine K-split partials. thread = (b, c, 4 pixels).
// ---------------------------------------------------------------------------
__global__ __launch_bounds__(256) void reduce_kernel(
    const float* __restrict__ opart, const float* __restrict__ mpart,
    const float* __restrict__ lpart, float* __restrict__ out, int ns)
{
    const int idx = blockIdx.x * 256 + threadIdx.x;   // 262144 quads
    const int nq  = idx & 1023;
    const int c   = (idx >> 10) & 31;
    const int b   = idx >> 15;
    const size_t noff = (size_t)nq * 4;

    f32x4 M;
    #pragma unroll
    for (int e = 0; e < 4; ++e) M[e] = -3.0e38f;
    for (int s = 0; s < ns; ++s) {
        f32x4 mm = *(const f32x4*)(mpart + ((size_t)(s * 8 + b)) * 4096 + noff);
        #pragma unroll
        for (int e = 0; e < 4; ++e) M[e] = fmaxf(M[e], mm[e]);
    }
    f32x4 L, O;
    #pragma unroll
    for (int e = 0; e < 4; ++e) { L[e] = 0.f; O[e] = 0.f; }
    for (int s = 0; s < ns; ++s) {
        f32x4 mm = *(const f32x4*)(mpart + ((size_t)(s * 8 + b)) * 4096 + noff);
        f32x4 ll = *(const f32x4*)(lpart + ((size_t)(s * 8 + b)) * 4096 + noff);
        f32x4 oo = *(const f32x4*)(opart + ((size_t)((s * 8 + b) * 32 + c)) * 4096 + noff);
        #pragma unroll
        for (int e = 0; e < 4; ++e) {
            float w = ex2(mm[e] - M[e]);
            L[e] += ll[e] * w;
            O[e] += oo[e] * w;
        }
    }
    f32x4 r;
    #pragma unroll
    for (int e = 0; e < 4; ++e) r[e] = O[e] / L[e];
    *(f32x4*)(out + ((size_t)(b * 32 + c)) * 4096 + noff) = r;
}

// ---------------------------------------------------------------------------
extern "C" void kernel_launch(void* const* d_in, const int* in_sizes, int n_in,
                              void* d_out, int out_size, void* d_ws, size_t ws_size,
                              hipStream_t stream)
{
    (void)in_sizes; (void)n_in; (void)out_size;
    const float* x  = (const float*)d_in[0];
    const float* Wk = (const float*)d_in[1];
    const float* bk = (const float*)d_in[2];
    const float* Wq = (const float*)d_in[3];
    const float* bq = (const float*)d_in[4];
    const float* Wv = (const float*)d_in[5];
    const float* bv = (const float*)d_in[6];
    float* out = (float*)d_out;

    char* ws = (char*)d_ws;
    const size_t SZ = (size_t)8 * 4096 * 32 * 2;   // 2 MB per bf16 buffer
    uint16_t* qhi = (uint16_t*)(ws);
    uint16_t* qlo = (uint16_t*)(ws + SZ);
    uint16_t* khi = (uint16_t*)(ws + 2 * SZ);
    uint16_t* klo = (uint16_t*)(ws + 3 * SZ);
    uint16_t* vt  = (uint16_t*)(ws + 4 * SZ);
    const size_t base = 5 * SZ;                    // 10 MB

    const size_t OB  = (size_t)8 * 32 * 4096 * 4;  // 4 MB per split (O^T)
    const size_t MB_ = (size_t)8 * 4096 * 4;       // 128 KB per split (m or l)
    int ns = 1;
    if      (ws_size >= base + 8 * (OB + 2 * MB_)) ns = 8;
    else if (ws_size >= base + 4 * (OB + 2 * MB_)) ns = 4;
    else if (ws_size >= base + 2 * (OB + 2 * MB_)) ns = 2;

    float* opart = (float*)(ws + base);
    float* mpart = (float*)(ws + base + (size_t)ns * OB);
    float* lpart = (float*)(ws + base + (size_t)ns * OB + (size_t)ns * MB_);

    proj_kernel<<<1024, 256, 0, stream>>>(x, Wk, bk, Wq, bq, Wv, bv,
                                          qhi, qlo, khi, klo, vt);
    attn_kernel<<<ns * 256, 256, 0, stream>>>(qhi, qlo, khi, klo, vt, out,
                                              opart, mpart, lpart, ns);
    if (ns > 1)
        reduce_kernel<<<1024, 256, 0, stream>>>(opart, mpart, lpart, out, ns);
}

// Round 7
// 65.536 us; speedup vs baseline: 3.6867x; 1.3408x over previous
//
#include <hip/hip_runtime.h>
#include <hip/hip_bf16.h>
#include <cstdint>
#include <cstddef>

// ---------------------------------------------------------------------------
// KQV2DPixel: 1x1-conv projections + flash attention, B=8, Cin=64, Cm=32,
// N=4096. fp32 in/out.
// R7: single-fp16 QK^T and PV (replaces split-bf16 3-term). Error budget:
// score err ~ sqrt(64)*2^-11 ~ 4e-3 -> absmax ~0.02 vs threshold 0.0894.
// QKT 12->4 MFMAs/tile, LDS ops/tile 60->40, staging 12->8 KB/tile.
// Skeleton = R2/R6: cooperative LDS staging, single buffer, 2 barriers/tile,
// log2-domain online softmax, cvt_pkrtz+permlane32_swap P-packing, ns-way
// K-split + reduce kernel. Launch bound (256,4): do NOT raise 2nd arg
// (R5 lesson: it caps VGPRs and forces scratch spills).
// ---------------------------------------------------------------------------

typedef _Float16 f16x8 __attribute__((ext_vector_type(8)));
typedef float  f32x16 __attribute__((ext_vector_type(16)));
typedef float  f32x4  __attribute__((ext_vector_type(4)));

struct alignas(16) U4 { uint32_t w[4]; };
struct alignas(8)  U2 { uint32_t w[2]; };

#define MFMA16(A, B, C) __builtin_amdgcn_mfma_f32_32x32x16_f16((A), (B), (C), 0, 0, 0)

__device__ __forceinline__ uint16_t f2h(float f) {       // RNE f32->f16
    _Float16 h = (_Float16)f;
    return __builtin_bit_cast(uint16_t, h);
}
__device__ __forceinline__ uint32_t cvtpk16(float lo, float hi) {  // RTZ pack
    auto h2 = __builtin_amdgcn_cvt_pkrtz(lo, hi);        // {lo16, hi16}
    return __builtin_bit_cast(uint32_t, h2);
}
__device__ __forceinline__ void swp(uint32_t& a, uint32_t& b) {
    asm("v_permlane32_swap_b32 %0, %1" : "+v"(a), "+v"(b));
}
__device__ __forceinline__ float ex2(float x) {   // 2^x
    float r;
    asm("v_exp_f32 %0, %1" : "=v"(r) : "v"(x));
    return r;
}
__device__ __forceinline__ float max3(float a, float b, float c) {
    return fmaxf(fmaxf(a, b), c);          // clang fuses to v_max3_f32
}
__device__ __forceinline__ f16x8 ld8(const void* p) {
    return __builtin_bit_cast(f16x8, *(const U4*)p);
}

// ---------------------------------------------------------------------------
// Kernel 1: projections. grid 1024 x 256; 8 threads/pixel, 4 outputs each.
// Output-quarter is wave-uniform -> W rows come via scalar loads.
//   q,k: fp16 [B][N][32]; q pre-scaled by log2(e).  v: fp16 [B][32][N].
// ---------------------------------------------------------------------------
__global__ __launch_bounds__(256) void proj_kernel(
    const float* __restrict__ x,
    const float* __restrict__ Wk, const float* __restrict__ bk,
    const float* __restrict__ Wq, const float* __restrict__ bq,
    const float* __restrict__ Wv, const float* __restrict__ bv,
    uint16_t* __restrict__ qf, uint16_t* __restrict__ kf,
    uint16_t* __restrict__ vt)
{
    const int g     = blockIdx.x * 256 + threadIdx.x;
    const int pixel = g & 32767;                                  // (b, n)
    const int qt    = __builtin_amdgcn_readfirstlane(g >> 15);    // 0..7, wave-uniform
    const int b     = pixel >> 12;
    const int n     = pixel & 4095;
    const int ob    = qt << 2;                                    // 4 outputs

    const float* xb = x + (size_t)b * 64 * 4096 + n;
    float xv[64];
    #pragma unroll
    for (int ci = 0; ci < 64; ++ci) xv[ci] = xb[(size_t)ci * 4096];

    #pragma unroll
    for (int pass = 0; pass < 3; ++pass) {
        const float* W    = pass == 0 ? Wk : (pass == 1 ? Wq : Wv);
        const float* bias = pass == 0 ? bk : (pass == 1 ? bq : bv);
        float acc[4];
        #pragma unroll
        for (int o = 0; o < 4; ++o) acc[o] = bias[ob + o];
        #pragma unroll
        for (int o = 0; o < 4; ++o) {
            const float* wr = W + (size_t)(ob + o) * 64;   // uniform -> s_load
            #pragma unroll
            for (int ci = 0; ci < 64; ++ci)
                acc[o] = fmaf(wr[ci], xv[ci], acc[o]);
        }
        if (pass == 2) {
            #pragma unroll
            for (int o = 0; o < 4; ++o)
                vt[((size_t)(b * 32 + ob + o)) * 4096 + n] = f2h(acc[o]);
        } else {
            if (pass == 1) {
                #pragma unroll
                for (int o = 0; o < 4; ++o) acc[o] *= 1.44269504f;   // log2(e)
            }
            U2 hp;
            #pragma unroll
            for (int j = 0; j < 2; ++j)
                hp.w[j] = (uint32_t)f2h(acc[2 * j]) | ((uint32_t)f2h(acc[2 * j + 1]) << 16);
            uint16_t* hd = (pass ? qf : kf) + ((size_t)(b * 4096 + n)) * 32 + ob;
            *(U2*)hd = hp;
        }
    }
}

// ---------------------------------------------------------------------------
// Kernel 2: flash attention with K-split. grid ns*256, 256 thr = 4 waves.
// b = blockIdx&7 (XCD-aligned). Per block: 128 q rows x (64/ns) 64-key tiles.
// Cooperative LDS staging (K 64x32 fp16 rows padded 80B; V^T 32x64 fp16 rows
// padded 144B), single buffer, 2 barriers/tile.
// ---------------------------------------------------------------------------
__global__ __launch_bounds__(256, 4) void attn_kernel(
    const uint16_t* __restrict__ qf, const uint16_t* __restrict__ kf,
    const uint16_t* __restrict__ vt, float* __restrict__ out,
    float* __restrict__ opart, float* __restrict__ mpart,
    float* __restrict__ lpart, int ns)
{
    __shared__ __align__(16) uint16_t lk[64 * 40];    // K tile, 80B rows (64B data)
    __shared__ __align__(16) uint16_t lv[32 * 72];    // V^T tile, 144B rows (128B data)

    const int blk    = blockIdx.x;
    const int b      = blk & 7;                 // XCD-aligned batch
    const int rest   = blk >> 3;
    const int qblk   = rest & 31;
    const int ksp    = rest >> 5;               // 0..ns-1
    const int ntiles = 64 / ns;
    const int kb0    = ksp * ntiles;
    const int kb1    = kb0 + ntiles;

    const int tid  = threadIdx.x;
    const int wv   = tid >> 6;
    const int lane = tid & 63;
    const int l31  = lane & 31;
    const int h32  = lane >> 5;
    const int qrow = qblk * 128 + wv * 32 + l31;

    // Q fragments: B-operand, col(lane&31)=q row, channels 8*h32+j (+16)
    f16x8 q0, q1;
    {
        const uint16_t* r = qf + ((size_t)(b * 4096 + qrow)) * 32;
        q0 = ld8(r + h32 * 8);
        q1 = ld8(r + 16 + h32 * 8);
    }

    f32x16 oacc;
    #pragma unroll
    for (int i = 0; i < 16; ++i) oacc[i] = 0.f;
    float m_run = -3.0e38f, l_run = 0.f;

    const U4* gk = (const U4*)(kf + ((size_t)b * 4096) * 32);   // 256 U4/tile
    const uint16_t* gv = vt + ((size_t)b * 32) * 4096;

    #pragma unroll 1
    for (int kb = kb0; kb < kb1; ++kb) {
        // ---- stage K (64x32 fp16 = 4 KB) and V^T (32x64 fp16 = 4 KB) ----
        {
            U4 a = gk[kb * 256 + tid];
            U4 v = *(const U4*)(gv + ((size_t)(tid >> 3)) * 4096 + kb * 64 + (tid & 7) * 8);
            *(U4*)((char*)lk + (tid >> 2) * 80 + (tid & 3) * 16) = a;
            *(U4*)((char*)lv + (tid >> 3) * 144 + (tid & 7) * 16) = v;
        }
        __syncthreads();

        // ---- QK^T, both 32-key halves (2 MFMAs each) ----
        f32x16 s0, s1;
        #pragma unroll
        for (int i = 0; i < 16; ++i) { s0[i] = 0.f; s1[i] = 0.f; }
        {
            const char* kr = (const char*)lk + l31 * 80 + h32 * 16;
            f16x8 a0 = ld8(kr);
            f16x8 a1 = ld8(kr + 32);
            const char* kr2 = (const char*)lk + (32 + l31) * 80 + h32 * 16;
            f16x8 c0 = ld8(kr2);
            f16x8 c1 = ld8(kr2 + 32);
            s0 = MFMA16(a0, q0, s0);
            s1 = MFMA16(c0, q0, s1);
            s0 = MFMA16(a1, q1, s0);
            s1 = MFMA16(c1, q1, s1);
        }

        // ---- one online-softmax update per 64 keys (log2 domain) ----
        float mx[4];
        #pragma unroll
        for (int i = 0; i < 4; ++i)
            mx[i] = max3(max3(s0[i], s0[i + 4], s0[i + 8]),
                         max3(s0[i + 12], s1[i], s1[i + 4]),
                         fmaxf(s1[i + 8], s1[i + 12]));
        float pm = fmaxf(max3(mx[0], mx[1], mx[2]), mx[3]);
        pm = fmaxf(pm, __shfl_xor(pm, 32));

        if (__any(pm > m_run)) {          // skip rescale when no row grew
            float mn  = fmaxf(m_run, pm);
            float scl = ex2(m_run - mn);
            l_run *= scl;
            #pragma unroll
            for (int i = 0; i < 16; ++i) oacc[i] *= scl;
            m_run = mn;
        }

        #pragma unroll
        for (int i = 0; i < 16; ++i) {
            s0[i] = ex2(s0[i] - m_run);
            s1[i] = ex2(s1[i] - m_run);
        }
        float sm[8];
        #pragma unroll
        for (int i = 0; i < 8; ++i)
            sm[i] = (s0[i] + s0[i + 8]) + (s1[i] + s1[i + 8]);
        #pragma unroll
        for (int i = 0; i < 4; ++i) sm[i] += sm[i + 4];
        float rs = (sm[0] + sm[2]) + (sm[1] + sm[3]);
        rs += __shfl_xor(rs, 32);
        l_run += rs;

        // ---- pack P -> 4 f16x8 B-fragments (cvt_pkrtz + permlane32_swap) ----
        U4 f1, f2, f3, f4;
        {
            uint32_t A = cvtpk16(s0[0], s0[1]),  B = cvtpk16(s0[4], s0[5]);   swp(A, B);
            uint32_t C = cvtpk16(s0[2], s0[3]),  D = cvtpk16(s0[6], s0[7]);   swp(C, D);
            f1.w[0] = A; f1.w[1] = C; f1.w[2] = B; f1.w[3] = D;
            A = cvtpk16(s0[8], s0[9]);   B = cvtpk16(s0[12], s0[13]);  swp(A, B);
            C = cvtpk16(s0[10], s0[11]); D = cvtpk16(s0[14], s0[15]);  swp(C, D);
            f2.w[0] = A; f2.w[1] = C; f2.w[2] = B; f2.w[3] = D;
            A = cvtpk16(s1[0], s1[1]);   B = cvtpk16(s1[4], s1[5]);    swp(A, B);
            C = cvtpk16(s1[2], s1[3]);   D = cvtpk16(s1[6], s1[7]);    swp(C, D);
            f3.w[0] = A; f3.w[1] = C; f3.w[2] = B; f3.w[3] = D;
            A = cvtpk16(s1[8], s1[9]);   B = cvtpk16(s1[12], s1[13]);  swp(A, B);
            C = cvtpk16(s1[10], s1[11]); D = cvtpk16(s1[14], s1[15]);  swp(C, D);
            f4.w[0] = A; f4.w[1] = C; f4.w[2] = B; f4.w[3] = D;
        }

        // ---- PV: O^T[c][q] += V^T * P^T  (4 MFMAs over 64 keys) ----
        {
            const char* vr = (const char*)lv + l31 * 144 + h32 * 16;
            f16x8 v0 = ld8(vr);
            f16x8 v1 = ld8(vr + 32);
            f16x8 v2 = ld8(vr + 64);
            f16x8 v3 = ld8(vr + 96);
            oacc = MFMA16(v0, __builtin_bit_cast(f16x8, f1), oacc);
            oacc = MFMA16(v1, __builtin_bit_cast(f16x8, f2), oacc);
            oacc = MFMA16(v2, __builtin_bit_cast(f16x8, f3), oacc);
            oacc = MFMA16(v3, __builtin_bit_cast(f16x8, f4), oacc);
        }
        __syncthreads();
    }

    // ---- epilogue ----
    if (ns == 1) {
        const float inv = 1.f / l_run;
        float* ob = out + ((size_t)b * 32) * 4096 + qrow;
        #pragma unroll
        for (int i = 0; i < 16; ++i) {
            int c = (i & 3) + 8 * (i >> 2) + 4 * h32;
            ob[(size_t)c * 4096] = oacc[i] * inv;
        }
    } else {
        float* op = opart + ((size_t)((ksp * 8 + b) * 32)) * 4096 + qrow;
        #pragma unroll
        for (int i = 0; i < 16; ++i) {
            int c = (i & 3) + 8 * (i >> 2) + 4 * h32;
            op[(size_t)c * 4096] = oacc[i];
        }
        if (h32 == 0) {
            mpart[((size_t)(ksp * 8 + b)) * 4096 + qrow] = m_run;
            lpart[((size_t)(ksp * 8 + b)) * 4096 + qrow] = l_run;
        }
    }
}

// ---------------------------------------------------------------------------
// Kernel 3: combine K-split partials. thread = (b, c, 4 pixels).
// ---------------------------------------------------------------------------
__global__ __launch_bounds__(256) void reduce_kernel(
    const float* __restrict__ opart, const float* __restrict__ mpart,
    const float* __restrict__ lpart, float* __restrict__ out, int ns)
{
    const int idx = blockIdx.x * 256 + threadIdx.x;   // 262144 quads
    const int nq  = idx & 1023;
    const int c   = (idx >> 10) & 31;
    const int b   = idx >> 15;
    const size_t noff = (size_t)nq * 4;

    f32x4 M;
    #pragma unroll
    for (int e = 0; e < 4; ++e) M[e] = -3.0e38f;
    for (int s = 0; s < ns; ++s) {
        f32x4 mm = *(const f32x4*)(mpart + ((size_t)(s * 8 + b)) * 4096 + noff);
        #pragma unroll
        for (int e = 0; e < 4; ++e) M[e] = fmaxf(M[e], mm[e]);
    }
    f32x4 L, O;
    #pragma unroll
    for (int e = 0; e < 4; ++e) { L[e] = 0.f; O[e] = 0.f; }
    for (int s = 0; s < ns; ++s) {
        f32x4 mm = *(const f32x4*)(mpart + ((size_t)(s * 8 + b)) * 4096 + noff);
        f32x4 ll = *(const f32x4*)(lpart + ((size_t)(s * 8 + b)) * 4096 + noff);
        f32x4 oo = *(const f32x4*)(opart + ((size_t)((s * 8 + b) * 32 + c)) * 4096 + noff);
        #pragma unroll
        for (int e = 0; e < 4; ++e) {
            float w = ex2(mm[e] - M[e]);
            L[e] += ll[e] * w;
            O[e] += oo[e] * w;
        }
    }
    f32x4 r;
    #pragma unroll
    for (int e = 0; e < 4; ++e) r[e] = O[e] / L[e];
    *(f32x4*)(out + ((size_t)(b * 32 + c)) * 4096 + noff) = r;
}

// ---------------------------------------------------------------------------
extern "C" void kernel_launch(void* const* d_in, const int* in_sizes, int n_in,
                              void* d_out, int out_size, void* d_ws, size_t ws_size,
                              hipStream_t stream)
{
    (void)in_sizes; (void)n_in; (void)out_size;
    const float* x  = (const float*)d_in[0];
    const float* Wk = (const float*)d_in[1];
    const float* bk = (const float*)d_in[2];
    const float* Wq = (const float*)d_in[3];
    const float* bq = (const float*)d_in[4];
    const float* Wv = (const float*)d_in[5];
    const float* bv = (const float*)d_in[6];
    float* out = (float*)d_out;

    char* ws = (char*)d_ws;
    const size_t SZ = (size_t)8 * 4096 * 32 * 2;   // 2 MB per fp16 buffer
    uint16_t* qf = (uint16_t*)(ws);
    uint16_t* kf = (uint16_t*)(ws + SZ);
    uint16_t* vt = (uint16_t*)(ws + 2 * SZ);
    const size_t base = 3 * SZ;                    // 6 MB

    const size_t OB  = (size_t)8 * 32 * 4096 * 4;  // 4 MB per split (O^T)
    const size_t MB_ = (size_t)8 * 4096 * 4;       // 128 KB per split (m or l)
    int ns = 1;
    if      (ws_size >= base + 8 * (OB + 2 * MB_)) ns = 8;
    else if (ws_size >= base + 4 * (OB + 2 * MB_)) ns = 4;
    else if (ws_size >= base + 2 * (OB + 2 * MB_)) ns = 2;

    float* opart = (float*)(ws + base);
    float* mpart = (float*)(ws + base + (size_t)ns * OB);
    float* lpart = (float*)(ws + base + (size_t)ns * OB + (size_t)ns * MB_);

    proj_kernel<<<1024, 256, 0, stream>>>(x, Wk, bk, Wq, bq, Wv, bv,
                                          qf, kf, vt);
    attn_kernel<<<ns * 256, 256, 0, stream>>>(qf, kf, vt, out,
                                              opart, mpart, lpart, ns);
    if (ns > 1)
        reduce_kernel<<<1024, 256, 0, stream>>>(opart, mpart, lpart, out, ns);
}

// Round 8
// 63.863 us; speedup vs baseline: 3.7833x; 1.0262x over previous
//
#include <hip/hip_runtime.h>
#include <hip/hip_bf16.h>
#include <cstdint>
#include <cstddef>

// ---------------------------------------------------------------------------
// KQV2DPixel: 1x1-conv projections + flash attention, B=8, Cin=64, Cm=32,
// N=4096. fp32 in/out. fp16 QK^T/PV (R7), log2-domain online softmax,
// cvt_pkrtz+permlane32_swap P-packing, K-split x ns + reduce kernel.
// R8: async staging via global_load_lds (no VGPR round-trip, no ds_write),
// double-buffered LDS, ONE __syncthreads per tile (its vmcnt(0) drain IS the
// pipeline wait, issued a full tile-compute earlier). Linear LDS layouts
// (gload_lds requirement) with XOR swizzle PRE-APPLIED IN GLOBAL by proj:
//   K row r (64B, 4 chunks of 16B): chunk c4 stored at c4 ^ (r&3)
//   V^T row c, 64-key segment (128B, 8 chunks): chunk c8 stored at c8 ^ (c&7)
// ds_read side applies the same XOR -> 8 bank-group-optimal access.
// ns=4 (R2 vs R6: attn parity; halves partials traffic).
// Launch bound (256,4): do NOT raise 2nd arg (R5: caps VGPR -> spills).
// ---------------------------------------------------------------------------

typedef _Float16 f16x8 __attribute__((ext_vector_type(8)));
typedef float  f32x16 __attribute__((ext_vector_type(16)));
typedef float  f32x4  __attribute__((ext_vector_type(4)));

struct alignas(16) U4 { uint32_t w[4]; };
struct alignas(8)  U2 { uint32_t w[2]; };

#define MFMA16(A, B, C) __builtin_amdgcn_mfma_f32_32x32x16_f16((A), (B), (C), 0, 0, 0)

__device__ __forceinline__ uint16_t f2h(float f) {       // RNE f32->f16
    _Float16 h = (_Float16)f;
    return __builtin_bit_cast(uint16_t, h);
}
__device__ __forceinline__ uint32_t cvtpk16(float lo, float hi) {  // RTZ pack
    auto h2 = __builtin_amdgcn_cvt_pkrtz(lo, hi);        // {lo16, hi16}
    return __builtin_bit_cast(uint32_t, h2);
}
__device__ __forceinline__ void swp(uint32_t& a, uint32_t& b) {
    asm("v_permlane32_swap_b32 %0, %1" : "+v"(a), "+v"(b));
}
__device__ __forceinline__ float ex2(float x) {   // 2^x
    float r;
    asm("v_exp_f32 %0, %1" : "=v"(r) : "v"(x));
    return r;
}
__device__ __forceinline__ float max3(float a, float b, float c) {
    return fmaxf(fmaxf(a, b), c);          // clang fuses to v_max3_f32
}
__device__ __forceinline__ f16x8 ld8(const void* p) {
    return __builtin_bit_cast(f16x8, *(const U4*)p);
}
// async global->LDS, 16B per lane. lds base is wave-uniform; HW adds lane*16.
__device__ __forceinline__ void gload16(const void* g, void* l) {
    __builtin_amdgcn_global_load_lds(
        (const __attribute__((address_space(1))) void*)g,
        (__attribute__((address_space(3))) void*)l, 16, 0, 0);
}

// ---------------------------------------------------------------------------
// Kernel 1: projections. grid 1024 x 256; 8 threads/pixel, 4 outputs each.
// Output-quarter is wave-uniform -> W rows come via scalar loads.
//   q: fp16 [B][N][32] (pre-scaled by log2(e)), plain layout.
//   k: fp16 [B][N][32] with 16B-chunk swizzle c4^(n&3) within each 64B row.
//   v: fp16 [B][32][N] with 16B-chunk swizzle c8^(c&7) within each 128B seg.
// ---------------------------------------------------------------------------
__global__ __launch_bounds__(256) void proj_kernel(
    const float* __restrict__ x,
    const float* __restrict__ Wk, const float* __restrict__ bk,
    const float* __restrict__ Wq, const float* __restrict__ bq,
    const float* __restrict__ Wv, const float* __restrict__ bv,
    uint16_t* __restrict__ qf, uint16_t* __restrict__ kf,
    uint16_t* __restrict__ vt)
{
    const int g     = blockIdx.x * 256 + threadIdx.x;
    const int pixel = g & 32767;                                  // (b, n)
    const int qt    = __builtin_amdgcn_readfirstlane(g >> 15);    // 0..7, wave-uniform
    const int b     = pixel >> 12;
    const int n     = pixel & 4095;
    const int ob    = qt << 2;                                    // 4 outputs

    const float* xb = x + (size_t)b * 64 * 4096 + n;
    float xv[64];
    #pragma unroll
    for (int ci = 0; ci < 64; ++ci) xv[ci] = xb[(size_t)ci * 4096];

    #pragma unroll
    for (int pass = 0; pass < 3; ++pass) {
        const float* W    = pass == 0 ? Wk : (pass == 1 ? Wq : Wv);
        const float* bias = pass == 0 ? bk : (pass == 1 ? bq : bv);
        float acc[4];
        #pragma unroll
        for (int o = 0; o < 4; ++o) acc[o] = bias[ob + o];
        #pragma unroll
        for (int o = 0; o < 4; ++o) {
            const float* wr = W + (size_t)(ob + o) * 64;   // uniform -> s_load
            #pragma unroll
            for (int ci = 0; ci < 64; ++ci)
                acc[o] = fmaf(wr[ci], xv[ci], acc[o]);
        }
        if (pass == 2) {
            #pragma unroll
            for (int o = 0; o < 4; ++o) {
                int c   = ob + o;
                int nsw = (n & ~0x38) | ((((n >> 3) & 7) ^ (c & 7)) << 3);
                vt[((size_t)(b * 32 + c)) * 4096 + nsw] = f2h(acc[o]);
            }
        } else {
            if (pass == 1) {
                #pragma unroll
                for (int o = 0; o < 4; ++o) acc[o] *= 1.44269504f;   // log2(e)
            }
            U2 hp;
            #pragma unroll
            for (int j = 0; j < 2; ++j)
                hp.w[j] = (uint32_t)f2h(acc[2 * j]) | ((uint32_t)f2h(acc[2 * j + 1]) << 16);
            if (pass == 0) {
                // swizzled K: row n, chunk (qt>>1) -> (qt>>1)^(n&3), half (qt&1)
                char* rowb = (char*)kf + ((size_t)(b * 4096 + n)) * 64;
                *(U2*)(rowb + (((qt >> 1) ^ (n & 3)) * 16) + (qt & 1) * 8) = hp;
            } else {
                uint16_t* hd = qf + ((size_t)(b * 4096 + n)) * 32 + ob;
                *(U2*)hd = hp;
            }
        }
    }
}

// ---------------------------------------------------------------------------
// Kernel 2: flash attention with K-split. grid ns*256, 256 thr = 4 waves.
// b = blockIdx&7 (XCD-aligned). Per block: 128 q rows x (64/ns) 64-key tiles.
// Async gload_lds staging, 2 LDS buffers, ONE __syncthreads per tile.
// Safety: reads of buf[t] complete before sync(t+1) (MFMA-consumed);
// writes for tile t+2 are issued after sync(t+1); sync's vmcnt(0) drains
// each wave's own loads, barrier makes it block-wide.
// ---------------------------------------------------------------------------
__global__ __launch_bounds__(256, 4) void attn_kernel(
    const uint16_t* __restrict__ qf, const uint16_t* __restrict__ kf,
    const uint16_t* __restrict__ vt, float* __restrict__ out,
    float* __restrict__ opart, float* __restrict__ mpart,
    float* __restrict__ lpart, int ns)
{
    __shared__ __align__(16) char lds_k[2][4096];   // K tile: 64 rows x 64B, linear
    __shared__ __align__(16) char lds_v[2][4096];   // V^T tile: 32 rows x 128B, linear

    const int blk    = blockIdx.x;
    const int b      = blk & 7;                 // XCD-aligned batch
    const int rest   = blk >> 3;
    const int qblk   = rest & 31;
    const int ksp    = rest >> 5;               // 0..ns-1
    const int ntiles = 64 / ns;
    const int kb0    = ksp * ntiles;
    const int kb1    = kb0 + ntiles;

    const int tid  = threadIdx.x;
    const int wv   = __builtin_amdgcn_readfirstlane(tid >> 6);  // wave-uniform
    const int lane = tid & 63;
    const int l31  = lane & 31;
    const int h32  = lane >> 5;
    const int qrow = qblk * 128 + wv * 32 + l31;

    // Q fragments: B-operand, col(lane&31)=q row, channels 8*h32+j (+16)
    f16x8 q0, q1;
    {
        const uint16_t* r = qf + ((size_t)(b * 4096 + qrow)) * 32;
        q0 = ld8(r + h32 * 8);
        q1 = ld8(r + 16 + h32 * 8);
    }

    f32x16 oacc;
    #pragma unroll
    for (int i = 0; i < 16; ++i) oacc[i] = 0.f;
    float m_run = -3.0e38f, l_run = 0.f;

    // staging source bases (per-lane). K tile kb = 4KB contiguous; wave wv
    // stages rows [wv*16, wv*16+16) = bytes wv*1024 + lane*16.
    const char* gk = (const char*)kf + ((size_t)b * 4096) * 64;
    // V: wave wv stages channels [wv*8, wv*8+8), lane covers (lane>>3)th
    // channel's (lane&7)th 16B chunk of the tile's 128B segment.
    const char* gv = (const char*)vt
                   + ((size_t)(b * 32 + wv * 8 + (lane >> 3))) * 8192
                   + (lane & 7) * 16;
    const char* gk_l = gk + wv * 1024 + lane * 16;

    // LDS read offsets (loop-invariant; XOR matches proj's global swizzle)
    const int ka0 = l31 * 64 + ((h32 ^ (l31 & 3)) * 16);            // ch 8h32..
    const int ka1 = l31 * 64 + (((2 + h32) ^ (l31 & 3)) * 16);      // ch 16+8h32..
    int vo[4];
    #pragma unroll
    for (int j = 0; j < 4; ++j)
        vo[j] = l31 * 128 + (((h32 + 2 * j) ^ (l31 & 7)) * 16);     // keys 16j+8h32..

    // ---- prologue: stage tile kb0 ----
    {
        gload16(gk_l + (size_t)kb0 * 4096, lds_k[kb0 & 1] + wv * 1024);
        gload16(gv   + (size_t)kb0 * 128,  lds_v[kb0 & 1] + wv * 1024);
    }

    #pragma unroll 2
    for (int kb = kb0; kb < kb1; ++kb) {
        const int cur = kb & 1;
        __syncthreads();   // drains own gload_lds (vmcnt 0) + block barrier

        if (kb + 1 < kb1) {   // issue next tile's staging (hides under compute)
            gload16(gk_l + (size_t)(kb + 1) * 4096, lds_k[cur ^ 1] + wv * 1024);
            gload16(gv   + (size_t)(kb + 1) * 128,  lds_v[cur ^ 1] + wv * 1024);
        }

        // ---- QK^T, both 32-key halves (2 MFMAs each) ----
        f32x16 s0, s1;
        #pragma unroll
        for (int i = 0; i < 16; ++i) { s0[i] = 0.f; s1[i] = 0.f; }
        {
            const char* lk = lds_k[cur];
            f16x8 a0 = ld8(lk + ka0);
            f16x8 a1 = ld8(lk + ka1);
            f16x8 c0 = ld8(lk + 2048 + ka0);
            f16x8 c1 = ld8(lk + 2048 + ka1);
            s0 = MFMA16(a0, q0, s0);
            s1 = MFMA16(c0, q0, s1);
            s0 = MFMA16(a1, q1, s0);
            s1 = MFMA16(c1, q1, s1);
        }

        // ---- one online-softmax update per 64 keys (log2 domain) ----
        float mx[4];
        #pragma unroll
        for (int i = 0; i < 4; ++i)
            mx[i] = max3(max3(s0[i], s0[i + 4], s0[i + 8]),
                         max3(s0[i + 12], s1[i], s1[i + 4]),
                         fmaxf(s1[i + 8], s1[i + 12]));
        float pm = fmaxf(max3(mx[0], mx[1], mx[2]), mx[3]);
        pm = fmaxf(pm, __shfl_xor(pm, 32));

        if (__any(pm > m_run)) {          // skip rescale when no row grew
            float mn  = fmaxf(m_run, pm);
            float scl = ex2(m_run - mn);
            l_run *= scl;
            #pragma unroll
            for (int i = 0; i < 16; ++i) oacc[i] *= scl;
            m_run = mn;
        }

        #pragma unroll
        for (int i = 0; i < 16; ++i) {
            s0[i] = ex2(s0[i] - m_run);
            s1[i] = ex2(s1[i] - m_run);
        }
        float sm[8];
        #pragma unroll
        for (int i = 0; i < 8; ++i)
            sm[i] = (s0[i] + s0[i + 8]) + (s1[i] + s1[i + 8]);
        #pragma unroll
        for (int i = 0; i < 4; ++i) sm[i] += sm[i + 4];
        float rs = (sm[0] + sm[2]) + (sm[1] + sm[3]);
        rs += __shfl_xor(rs, 32);
        l_run += rs;

        // ---- pack P -> 4 f16x8 B-fragments (cvt_pkrtz + permlane32_swap) ----
        U4 f1, f2, f3, f4;
        {
            uint32_t A = cvtpk16(s0[0], s0[1]),  B = cvtpk16(s0[4], s0[5]);   swp(A, B);
            uint32_t C = cvtpk16(s0[2], s0[3]),  D = cvtpk16(s0[6], s0[7]);   swp(C, D);
            f1.w[0] = A; f1.w[1] = C; f1.w[2] = B; f1.w[3] = D;
            A = cvtpk16(s0[8], s0[9]);   B = cvtpk16(s0[12], s0[13]);  swp(A, B);
            C = cvtpk16(s0[10], s0[11]); D = cvtpk16(s0[14], s0[15]);  swp(C, D);
            f2.w[0] = A; f2.w[1] = C; f2.w[2] = B; f2.w[3] = D;
            A = cvtpk16(s1[0], s1[1]);   B = cvtpk16(s1[4], s1[5]);    swp(A, B);
            C = cvtpk16(s1[2], s1[3]);   D = cvtpk16(s1[6], s1[7]);    swp(C, D);
            f3.w[0] = A; f3.w[1] = C; f3.w[2] = B; f3.w[3] = D;
            A = cvtpk16(s1[8], s1[9]);   B = cvtpk16(s1[12], s1[13]);  swp(A, B);
            C = cvtpk16(s1[10], s1[11]); D = cvtpk16(s1[14], s1[15]);  swp(C, D);
            f4.w[0] = A; f4.w[1] = C; f4.w[2] = B; f4.w[3] = D;
        }

        // ---- PV: O^T[c][q] += V^T * P^T  (4 MFMAs over 64 keys) ----
        {
            const char* lv = lds_v[cur];
            f16x8 v0 = ld8(lv + vo[0]);
            f16x8 v1 = ld8(lv + vo[1]);
            f16x8 v2 = ld8(lv + vo[2]);
            f16x8 v3 = ld8(lv + vo[3]);
            oacc = MFMA16(v0, __builtin_bit_cast(f16x8, f1), oacc);
            oacc = MFMA16(v1, __builtin_bit_cast(f16x8, f2), oacc);
            oacc = MFMA16(v2, __builtin_bit_cast(f16x8, f3), oacc);
            oacc = MFMA16(v3, __builtin_bit_cast(f16x8, f4), oacc);
        }
    }

    // ---- epilogue ----
    if (ns == 1) {
        const float inv = 1.f / l_run;
        float* ob = out + ((size_t)b * 32) * 4096 + qrow;
        #pragma unroll
        for (int i = 0; i < 16; ++i) {
            int c = (i & 3) + 8 * (i >> 2) + 4 * h32;
            ob[(size_t)c * 4096] = oacc[i] * inv;
        }
    } else {
        float* op = opart + ((size_t)((ksp * 8 + b) * 32)) * 4096 + qrow;
        #pragma unroll
        for (int i = 0; i < 16; ++i) {
            int c = (i & 3) + 8 * (i >> 2) + 4 * h32;
            op[(size_t)c * 4096] = oacc[i];
        }
        if (h32 == 0) {
            mpart[((size_t)(ksp * 8 + b)) * 4096 + qrow] = m_run;
            lpart[((size_t)(ksp * 8 + b)) * 4096 + qrow] = l_run;
        }
    }
}

// ---------------------------------------------------------------------------
// Kernel 3: combine K-split partials. thread = (b, c, 4 pixels).
// ---------------------------------------------------------------------------
__global__ __launch_bounds__(256) void reduce_kernel(
    const float* __restrict__ opart, const float* __restrict__ mpart,
    const float* __restrict__ lpart, float* __restrict__ out, int ns)
{
    const int idx = blockIdx.x * 256 + threadIdx.x;   // 262144 quads
    const int nq  = idx & 1023;
    const int c   = (idx >> 10) & 31;
    const int b   = idx >> 15;
    const size_t noff = (size_t)nq * 4;

    f32x4 M;
    #pragma unroll
    for (int e = 0; e < 4; ++e) M[e] = -3.0e38f;
    for (int s = 0; s < ns; ++s) {
        f32x4 mm = *(const f32x4*)(mpart + ((size_t)(s * 8 + b)) * 4096 + noff);
        #pragma unroll
        for (int e = 0; e < 4; ++e) M[e] = fmaxf(M[e], mm[e]);
    }
    f32x4 L, O;
    #pragma unroll
    for (int e = 0; e < 4; ++e) { L[e] = 0.f; O[e] = 0.f; }
    for (int s = 0; s < ns; ++s) {
        f32x4 mm = *(const f32x4*)(mpart + ((size_t)(s * 8 + b)) * 4096 + noff);
        f32x4 ll = *(const f32x4*)(lpart + ((size_t)(s * 8 + b)) * 4096 + noff);
        f32x4 oo = *(const f32x4*)(opart + ((size_t)((s * 8 + b) * 32 + c)) * 4096 + noff);
        #pragma unroll
        for (int e = 0; e < 4; ++e) {
            float w = ex2(mm[e] - M[e]);
            L[e] += ll[e] * w;
            O[e] += oo[e] * w;
        }
    }
    f32x4 r;
    #pragma unroll
    for (int e = 0; e < 4; ++e) r[e] = O[e] / L[e];
    *(f32x4*)(out + ((size_t)(b * 32 + c)) * 4096 + noff) = r;
}

// ---------------------------------------------------------------------------
extern "C" void kernel_launch(void* const* d_in, const int* in_sizes, int n_in,
                              void* d_out, int out_size, void* d_ws, size_t ws_size,
                              hipStream_t stream)
{
    (void)in_sizes; (void)n_in; (void)out_size;
    const float* x  = (const float*)d_in[0];
    const float* Wk = (const float*)d_in[1];
    const float* bk = (const float*)d_in[2];
    const float* Wq = (const float*)d_in[3];
    const float* bq = (const float*)d_in[4];
    const float* Wv = (const float*)d_in[5];
    const float* bv = (const float*)d_in[6];
    float* out = (float*)d_out;

    char* ws = (char*)d_ws;
    const size_t SZ = (size_t)8 * 4096 * 32 * 2;   // 2 MB per fp16 buffer
    uint16_t* qf = (uint16_t*)(ws);
    uint16_t* kf = (uint16_t*)(ws + SZ);
    uint16_t* vt = (uint16_t*)(ws + 2 * SZ);
    const size_t base = 3 * SZ;                    // 6 MB

    const size_t OB  = (size_t)8 * 32 * 4096 * 4;  // 4 MB per split (O^T)
    const size_t MB_ = (size_t)8 * 4096 * 4;       // 128 KB per split (m or l)
    int ns = 1;
    if      (ws_size >= base + 4 * (OB + 2 * MB_)) ns = 4;
    else if (ws_size >= base + 2 * (OB + 2 * MB_)) ns = 2;

    float* opart = (float*)(ws + base);
    float* mpart = (float*)(ws + base + (size_t)ns * OB);
    float* lpart = (float*)(ws + base + (size_t)ns * OB + (size_t)ns * MB_);

    proj_kernel<<<1024, 256, 0, stream>>>(x, Wk, bk, Wq, bq, Wv, bv,
                                          qf, kf, vt);
    attn_kernel<<<ns * 256, 256, 0, stream>>>(qf, kf, vt, out,
                                              opart, mpart, lpart, ns);
    if (ns > 1)
        reduce_kernel<<<1024, 256, 0, stream>>>(opart, mpart, lpart, out, ns);
}

// Round 10
// 62.306 us; speedup vs baseline: 3.8778x; 1.0250x over previous
//
#include <hip/hip_runtime.h>
#include <hip/hip_bf16.h>
#include <cstdint>
#include <cstddef>

// ---------------------------------------------------------------------------
// KQV2DPixel: 1x1-conv projections + flash attention, B=8, Cin=64, Cm=32,
// N=4096. fp32 in/out. fp16 QK^T/PV, log2-domain online softmax,
// cvt_pkrtz+permlane32_swap P-packing, K-split x ns + reduce kernel.
// R10: base = R8 (known-good, 63.9us; R9's no-max experiment failed
// unexplainedly and is fully reverted). Two safe changes:
//  (1) paired tiles -- ONE __syncthreads per TWO 64-key tiles, 2x2 LDS
//      buffer slots (32 KB). Stage next pair (4 gload_lds) after the sync,
//      compute both tiles of the current pair. Same race structure as R8.
//  (2) defer-max (T13): rescale only when __any(pm > m_run + 6); skipped
//      tiles produce P = exp2(s - m_run) <= 2^6 = 64, safe in fp16.
// Launch bound (256,4): do NOT raise 2nd arg (R5: caps VGPR -> spills).
// ---------------------------------------------------------------------------

typedef _Float16 f16x8 __attribute__((ext_vector_type(8)));
typedef float  f32x16 __attribute__((ext_vector_type(16)));
typedef float  f32x4  __attribute__((ext_vector_type(4)));

struct alignas(16) U4 { uint32_t w[4]; };
struct alignas(8)  U2 { uint32_t w[2]; };

#define MFMA16(A, B, C) __builtin_amdgcn_mfma_f32_32x32x16_f16((A), (B), (C), 0, 0, 0)

__device__ __forceinline__ uint16_t f2h(float f) {       // RNE f32->f16
    _Float16 h = (_Float16)f;
    return __builtin_bit_cast(uint16_t, h);
}
__device__ __forceinline__ uint32_t cvtpk16(float lo, float hi) {  // RTZ pack
    auto h2 = __builtin_amdgcn_cvt_pkrtz(lo, hi);        // {lo16, hi16}
    return __builtin_bit_cast(uint32_t, h2);
}
__device__ __forceinline__ void swp(uint32_t& a, uint32_t& b) {
    asm("v_permlane32_swap_b32 %0, %1" : "+v"(a), "+v"(b));
}
__device__ __forceinline__ float ex2(float x) {   // 2^x
    float r;
    asm("v_exp_f32 %0, %1" : "=v"(r) : "v"(x));
    return r;
}
__device__ __forceinline__ float max3(float a, float b, float c) {
    return fmaxf(fmaxf(a, b), c);          // clang fuses to v_max3_f32
}
__device__ __forceinline__ f16x8 ld8(const void* p) {
    return __builtin_bit_cast(f16x8, *(const U4*)p);
}
// async global->LDS, 16B per lane. lds base is wave-uniform; HW adds lane*16.
__device__ __forceinline__ void gload16(const void* g, void* l) {
    __builtin_amdgcn_global_load_lds(
        (const __attribute__((address_space(1))) void*)g,
        (__attribute__((address_space(3))) void*)l, 16, 0, 0);
}

// ---------------------------------------------------------------------------
// Kernel 1: projections. grid 1024 x 256; 8 threads/pixel, 4 outputs each.
// Output-quarter is wave-uniform -> W rows come via scalar loads.
//   q: fp16 [B][N][32] (pre-scaled by log2(e)), plain layout.
//   k: fp16 [B][N][32] with 16B-chunk swizzle c4^(n&3) within each 64B row.
//   v: fp16 [B][32][N] with 16B-chunk swizzle c8^(c&7) within each 128B seg.
// ---------------------------------------------------------------------------
__global__ __launch_bounds__(256) void proj_kernel(
    const float* __restrict__ x,
    const float* __restrict__ Wk, const float* __restrict__ bk,
    const float* __restrict__ Wq, const float* __restrict__ bq,
    const float* __restrict__ Wv, const float* __restrict__ bv,
    uint16_t* __restrict__ qf, uint16_t* __restrict__ kf,
    uint16_t* __restrict__ vt)
{
    const int g     = blockIdx.x * 256 + threadIdx.x;
    const int pixel = g & 32767;                                  // (b, n)
    const int qt    = __builtin_amdgcn_readfirstlane(g >> 15);    // 0..7, wave-uniform
    const int b     = pixel >> 12;
    const int n     = pixel & 4095;
    const int ob    = qt << 2;                                    // 4 outputs

    const float* xb = x + (size_t)b * 64 * 4096 + n;
    float xv[64];
    #pragma unroll
    for (int ci = 0; ci < 64; ++ci) xv[ci] = xb[(size_t)ci * 4096];

    #pragma unroll
    for (int pass = 0; pass < 3; ++pass) {
        const float* W    = pass == 0 ? Wk : (pass == 1 ? Wq : Wv);
        const float* bias = pass == 0 ? bk : (pass == 1 ? bq : bv);
        float acc[4];
        #pragma unroll
        for (int o = 0; o < 4; ++o) acc[o] = bias[ob + o];
        #pragma unroll
        for (int o = 0; o < 4; ++o) {
            const float* wr = W + (size_t)(ob + o) * 64;   // uniform -> s_load
            #pragma unroll
            for (int ci = 0; ci < 64; ++ci)
                acc[o] = fmaf(wr[ci], xv[ci], acc[o]);
        }
        if (pass == 2) {
            #pragma unroll
            for (int o = 0; o < 4; ++o) {
                int c   = ob + o;
                int nsw = (n & ~0x38) | ((((n >> 3) & 7) ^ (c & 7)) << 3);
                vt[((size_t)(b * 32 + c)) * 4096 + nsw] = f2h(acc[o]);
            }
        } else {
            if (pass == 1) {
                #pragma unroll
                for (int o = 0; o < 4; ++o) acc[o] *= 1.44269504f;   // log2(e)
            }
            U2 hp;
            #pragma unroll
            for (int j = 0; j < 2; ++j)
                hp.w[j] = (uint32_t)f2h(acc[2 * j]) | ((uint32_t)f2h(acc[2 * j + 1]) << 16);
            if (pass == 0) {
                // swizzled K: row n, chunk (qt>>1) -> (qt>>1)^(n&3), half (qt&1)
                char* rowb = (char*)kf + ((size_t)(b * 4096 + n)) * 64;
                *(U2*)(rowb + (((qt >> 1) ^ (n & 3)) * 16) + (qt & 1) * 8) = hp;
            } else {
                uint16_t* hd = qf + ((size_t)(b * 4096 + n)) * 32 + ob;
                *(U2*)hd = hp;
            }
        }
    }
}

// ---------------------------------------------------------------------------
// Kernel 2: flash attention with K-split. grid ns*256, 256 thr = 4 waves.
// b = blockIdx&7 (XCD-aligned). Per block: 128 q rows x (64/ns) 64-key tiles,
// processed TWO per barrier. 2 pairs x 2 slots of LDS buffers (32 KB).
// ---------------------------------------------------------------------------
__global__ __launch_bounds__(256, 4) void attn_kernel(
    const uint16_t* __restrict__ qf, const uint16_t* __restrict__ kf,
    const uint16_t* __restrict__ vt, float* __restrict__ out,
    float* __restrict__ opart, float* __restrict__ mpart,
    float* __restrict__ lpart, int ns)
{
    __shared__ __align__(16) char lds_k[2][2][4096];   // [pair][slot] K 64x64B
    __shared__ __align__(16) char lds_v[2][2][4096];   // [pair][slot] V^T 32x128B

    const int blk    = blockIdx.x;
    const int b      = blk & 7;                 // XCD-aligned batch
    const int rest   = blk >> 3;
    const int qblk   = rest & 31;
    const int ksp    = rest >> 5;               // 0..ns-1
    const int ntiles = 64 / ns;                 // even for all ns
    const int kb0    = ksp * ntiles;
    const int niter  = ntiles >> 1;

    const int tid  = threadIdx.x;
    const int wv   = __builtin_amdgcn_readfirstlane(tid >> 6);  // wave-uniform
    const int lane = tid & 63;
    const int l31  = lane & 31;
    const int h32  = lane >> 5;
    const int qrow = qblk * 128 + wv * 32 + l31;

    // Q fragments: B-operand, col(lane&31)=q row, channels 8*h32+j (+16)
    f16x8 q0, q1;
    {
        const uint16_t* r = qf + ((size_t)(b * 4096 + qrow)) * 32;
        q0 = ld8(r + h32 * 8);
        q1 = ld8(r + 16 + h32 * 8);
    }

    f32x16 oacc, zf;
    #pragma unroll
    for (int i = 0; i < 16; ++i) { oacc[i] = 0.f; zf[i] = 0.f; }
    float m_run = -3.0e38f, l_run = 0.f;

    // staging source bases (per-lane).
    const char* gk   = (const char*)kf + ((size_t)b * 4096) * 64;
    const char* gv   = (const char*)vt
                     + ((size_t)(b * 32 + wv * 8 + (lane >> 3))) * 8192
                     + (lane & 7) * 16;
    const char* gk_l = gk + wv * 1024 + lane * 16;

    // LDS read offsets (loop-invariant; XOR matches proj's global swizzle)
    const int ka0 = l31 * 64 + ((h32 ^ (l31 & 3)) * 16);            // ch 8h32..
    const int ka1 = l31 * 64 + (((2 + h32) ^ (l31 & 3)) * 16);      // ch 16+8h32..
    int vo[4];
    #pragma unroll
    for (int j = 0; j < 4; ++j)
        vo[j] = l31 * 128 + (((h32 + 2 * j) ^ (l31 & 7)) * 16);     // keys 16j+8h32..

    // ---- prologue: stage tiles kb0, kb0+1 into pair 0 ----
    gload16(gk_l + (size_t)kb0 * 4096,       lds_k[0][0] + wv * 1024);
    gload16(gv   + (size_t)kb0 * 128,        lds_v[0][0] + wv * 1024);
    gload16(gk_l + (size_t)(kb0 + 1) * 4096, lds_k[0][1] + wv * 1024);
    gload16(gv   + (size_t)(kb0 + 1) * 128,  lds_v[0][1] + wv * 1024);

    int p = 0;
    #pragma unroll 1
    for (int it = 0; it < niter; ++it) {
        __syncthreads();   // drains own gload_lds (vmcnt 0) + block barrier

        if (it + 1 < niter) {   // stage next pair (hides under 2-tile compute)
            const int tn = kb0 + 2 * it + 2;
            gload16(gk_l + (size_t)tn * 4096,       lds_k[p ^ 1][0] + wv * 1024);
            gload16(gv   + (size_t)tn * 128,        lds_v[p ^ 1][0] + wv * 1024);
            gload16(gk_l + (size_t)(tn + 1) * 4096, lds_k[p ^ 1][1] + wv * 1024);
            gload16(gv   + (size_t)(tn + 1) * 128,  lds_v[p ^ 1][1] + wv * 1024);
        }

        #pragma unroll
        for (int sl = 0; sl < 2; ++sl) {
            const char* lk = lds_k[p][sl];
            const char* lv = lds_v[p][sl];

            // ---- QK^T, both 32-key halves (2 MFMAs each, zero-C in) ----
            f32x16 s0, s1;
            {
                f16x8 a0 = ld8(lk + ka0);
                f16x8 a1 = ld8(lk + ka1);
                f16x8 c0 = ld8(lk + 2048 + ka0);
                f16x8 c1 = ld8(lk + 2048 + ka1);
                s0 = MFMA16(a0, q0, zf);
                s1 = MFMA16(c0, q0, zf);
                s0 = MFMA16(a1, q1, s0);
                s1 = MFMA16(c1, q1, s1);
            }

            // ---- online softmax, defer-max threshold 6 (log2 domain) ----
            float mx[4];
            #pragma unroll
            for (int i = 0; i < 4; ++i)
                mx[i] = max3(max3(s0[i], s0[i + 4], s0[i + 8]),
                             max3(s0[i + 12], s1[i], s1[i + 4]),
                             fmaxf(s1[i + 8], s1[i + 12]));
            float pm = fmaxf(max3(mx[0], mx[1], mx[2]), mx[3]);
            pm = fmaxf(pm, __shfl_xor(pm, 32));

            if (__any(pm > m_run + 6.f)) {   // rescale only on real growth
                float mn  = fmaxf(m_run, pm);
                float scl = ex2(m_run - mn);
                l_run *= scl;
                #pragma unroll
                for (int i = 0; i < 16; ++i) oacc[i] *= scl;
                m_run = mn;
            }
            // P = exp2(s - m_run) <= 2^6 = 64: safe in fp16 (max 65504)

            #pragma unroll
            for (int i = 0; i < 16; ++i) {
                s0[i] = ex2(s0[i] - m_run);
                s1[i] = ex2(s1[i] - m_run);
            }
            float sm[8];
            #pragma unroll
            for (int i = 0; i < 8; ++i)
                sm[i] = (s0[i] + s0[i + 8]) + (s1[i] + s1[i + 8]);
            #pragma unroll
            for (int i = 0; i < 4; ++i) sm[i] += sm[i + 4];
            float rs = (sm[0] + sm[2]) + (sm[1] + sm[3]);
            rs += __shfl_xor(rs, 32);
            l_run += rs;

            // ---- pack P -> 4 f16x8 B-frags (cvt_pkrtz + permlane) ----
            U4 f1, f2, f3, f4;
            {
                uint32_t A = cvtpk16(s0[0], s0[1]),  B = cvtpk16(s0[4], s0[5]);   swp(A, B);
                uint32_t C = cvtpk16(s0[2], s0[3]),  D = cvtpk16(s0[6], s0[7]);   swp(C, D);
                f1.w[0] = A; f1.w[1] = C; f1.w[2] = B; f1.w[3] = D;
                A = cvtpk16(s0[8], s0[9]);   B = cvtpk16(s0[12], s0[13]);  swp(A, B);
                C = cvtpk16(s0[10], s0[11]); D = cvtpk16(s0[14], s0[15]);  swp(C, D);
                f2.w[0] = A; f2.w[1] = C; f2.w[2] = B; f2.w[3] = D;
                A = cvtpk16(s1[0], s1[1]);   B = cvtpk16(s1[4], s1[5]);    swp(A, B);
                C = cvtpk16(s1[2], s1[3]);   D = cvtpk16(s1[6], s1[7]);    swp(C, D);
                f3.w[0] = A; f3.w[1] = C; f3.w[2] = B; f3.w[3] = D;
                A = cvtpk16(s1[8], s1[9]);   B = cvtpk16(s1[12], s1[13]);  swp(A, B);
                C = cvtpk16(s1[10], s1[11]); D = cvtpk16(s1[14], s1[15]);  swp(C, D);
                f4.w[0] = A; f4.w[1] = C; f4.w[2] = B; f4.w[3] = D;
            }

            // ---- PV: O^T[c][q] += V^T * P^T  (4 MFMAs over 64 keys) ----
            {
                f16x8 v0 = ld8(lv + vo[0]);
                f16x8 v1 = ld8(lv + vo[1]);
                f16x8 v2 = ld8(lv + vo[2]);
                f16x8 v3 = ld8(lv + vo[3]);
                oacc = MFMA16(v0, __builtin_bit_cast(f16x8, f1), oacc);
                oacc = MFMA16(v1, __builtin_bit_cast(f16x8, f2), oacc);
                oacc = MFMA16(v2, __builtin_bit_cast(f16x8, f3), oacc);
                oacc = MFMA16(v3, __builtin_bit_cast(f16x8, f4), oacc);
            }
        }
        p ^= 1;
    }

    // ---- epilogue ----
    if (ns == 1) {
        const float inv = 1.f / l_run;
        float* ob = out + ((size_t)b * 32) * 4096 + qrow;
        #pragma unroll
        for (int i = 0; i < 16; ++i) {
            int c = (i & 3) + 8 * (i >> 2) + 4 * h32;
            ob[(size_t)c * 4096] = oacc[i] * inv;
        }
    } else {
        float* op = opart + ((size_t)((ksp * 8 + b) * 32)) * 4096 + qrow;
        #pragma unroll
        for (int i = 0; i < 16; ++i) {
            int c = (i & 3) + 8 * (i >> 2) + 4 * h32;
            op[(size_t)c * 4096] = oacc[i];
        }
        if (h32 == 0) {
            mpart[((size_t)(ksp * 8 + b)) * 4096 + qrow] = m_run;
            lpart[((size_t)(ksp * 8 + b)) * 4096 + qrow] = l_run;
        }
    }
}

// ---------------------------------------------------------------------------
// Kernel 3: combine K-split partials. thread = (b, c, 4 pixels).
// ---------------------------------------------------------------------------
__global__ __launch_bounds__(256) void reduce_kernel(
    const float* __restrict__ opart, const float* __restrict__ mpart,
    const float* __restrict__ lpart, float* __restrict__ out, int ns)
{
    const int idx = blockIdx.x * 256 + threadIdx.x;   // 262144 quads
    const int nq  = idx & 1023;
    const int c   = (idx >> 10) & 31;
    const int b   = idx >> 15;
    const size_t noff = (size_t)nq * 4;

    f32x4 M;
    #pragma unroll
    for (int e = 0; e < 4; ++e) M[e] = -3.0e38f;
    for (int s = 0; s < ns; ++s) {
        f32x4 mm = *(const f32x4*)(mpart + ((size_t)(s * 8 + b)) * 4096 + noff);
        #pragma unroll
        for (int e = 0; e < 4; ++e) M[e] = fmaxf(M[e], mm[e]);
    }
    f32x4 L, O;
    #pragma unroll
    for (int e = 0; e < 4; ++e) { L[e] = 0.f; O[e] = 0.f; }
    for (int s = 0; s < ns; ++s) {
        f32x4 mm = *(const f32x4*)(mpart + ((size_t)(s * 8 + b)) * 4096 + noff);
        f32x4 ll = *(const f32x4*)(lpart + ((size_t)(s * 8 + b)) * 4096 + noff);
        f32x4 oo = *(const f32x4*)(opart + ((size_t)((s * 8 + b) * 32 + c)) * 4096 + noff);
        #pragma unroll
        for (int e = 0; e < 4; ++e) {
            float w = ex2(mm[e] - M[e]);
            L[e] += ll[e] * w;
            O[e] += oo[e] * w;
        }
    }
    f32x4 r;
    #pragma unroll
    for (int e = 0; e < 4; ++e) r[e] = O[e] / L[e];
    *(f32x4*)(out + ((size_t)(b * 32 + c)) * 4096 + noff) = r;
}

// ---------------------------------------------------------------------------
extern "C" void kernel_launch(void* const* d_in, const int* in_sizes, int n_in,
                              void* d_out, int out_size, void* d_ws, size_t ws_size,
                              hipStream_t stream)
{
    (void)in_sizes; (void)n_in; (void)out_size;
    const float* x  = (const float*)d_in[0];
    const float* Wk = (const float*)d_in[1];
    const float* bk = (const float*)d_in[2];
    const float* Wq = (const float*)d_in[3];
    const float* bq = (const float*)d_in[4];
    const float* Wv = (const float*)d_in[5];
    const float* bv = (const float*)d_in[6];
    float* out = (float*)d_out;

    char* ws = (char*)d_ws;
    const size_t SZ = (size_t)8 * 4096 * 32 * 2;   // 2 MB per fp16 buffer
    uint16_t* qf = (uint16_t*)(ws);
    uint16_t* kf = (uint16_t*)(ws + SZ);
    uint16_t* vt = (uint16_t*)(ws + 2 * SZ);
    const size_t base = 3 * SZ;                    // 6 MB

    const size_t OB  = (size_t)8 * 32 * 4096 * 4;  // 4 MB per split (O^T)
    const size_t MB_ = (size_t)8 * 4096 * 4;       // 128 KB per split (m or l)
    int ns = 1;
    if      (ws_size >= base + 4 * (OB + 2 * MB_)) ns = 4;
    else if (ws_size >= base + 2 * (OB + 2 * MB_)) ns = 2;

    float* opart = (float*)(ws + base);
    float* mpart = (float*)(ws + base + (size_t)ns * OB);
    float* lpart = (float*)(ws + base + (size_t)ns * OB + (size_t)ns * MB_);

    proj_kernel<<<1024, 256, 0, stream>>>(x, Wk, bk, Wq, bq, Wv, bv,
                                          qf, kf, vt);
    attn_kernel<<<ns * 256, 256, 0, stream>>>(qf, kf, vt, out,
                                              opart, mpart, lpart, ns);
    if (ns > 1)
        reduce_kernel<<<1024, 256, 0, stream>>>(opart, mpart, lpart, out, ns);
}